// Round 9
// baseline (587.434 us; speedup 1.0000x reference)
//
#include <hip/hip_runtime.h>

// Local cost-volume correlation, LDS-staged, all-81-outputs-per-block.
// out[b, dy*9+dx, h, w] = (1/256) sum_c in1[b,c,h,w] * in2[b,c,h+dy-4,w+dx-4]
//
// R12 design (from R11 post-mortem: R8 at 160us moves 1.78 GB global->L1
// = 19 B/cyc/CU == the copy-bench's per-CU L1 ceiling. ILP/occupancy/LDS-
// size all null because the kernel is L1-THROUGHPUT-bound on 9x-redundant
// loads. Fix: stage each tile's data in LDS ONCE, compute all 81 (dy,dx)):
//  - block = (b, 2-row band), 576 thr = 9 waves = ONE WAVE PER DY (uniform)
//  - thread = (pxg: 4 px, row, dy): acc[9][4] = 36 regs (R4-proven core)
//  - per 8-chan chunk: stage in1 2 rows + in2 10 rows (clamped halo) into
//    lds[8][12][132] = 50.7 KB (pad 132: b128-friendly, bank-spread)
//  - per channel per thread: 2 ds_read_b128 + 8 DPP window + 36 FMA
//  - global traffic 1.78 GB -> 0.60 GB (in1 1x, in2 5x); compute fed from
//    LDS (69 TB/s) instead of the saturated L1 path
//  - staging software-pipelined: next chunk's 6 float4 loads issue before
//    compute of current chunk (T14-style split); 2 barriers/chunk
//  - b = blockIdx&7 -> one batch image per XCD (L2 halo reuse)
//  - all arrays statically indexed via full unroll (R5/R6 scratch lesson)

#define CH 256
#define HH 96
#define WW 128
#define CS (HH * WW)
#define KC 8              // channels per chunk
#define NCHUNK (CH / KC)  // 32
#define SLOTS 12          // 2 in1 rows + 10 in2 rows
#define LDW 132           // padded row stride (floats)
#define PIECES (KC * SLOTS * 32)  // 3072 float4 pieces per chunk

__device__ __forceinline__ float wshr1(float x) {  // lane i <- lane i-1
  union { float f; int i; } u, o;
  u.f = x;
  o.i = __builtin_amdgcn_update_dpp(0, u.i, 0x138, 0xF, 0xF, true);
  return o.f;
}
__device__ __forceinline__ float wshl1(float x) {  // lane i <- lane i+1
  union { float f; int i; } u, o;
  u.f = x;
  o.i = __builtin_amdgcn_update_dpp(0, u.i, 0x130, 0xF, 0xF, true);
  return o.f;
}

__global__ __launch_bounds__(576, 4) void corr_lds(
    const float* __restrict__ in1, const float* __restrict__ in2,
    float* __restrict__ out)
{
  // ---- block decode: b = XCD (one image per XCD), band of 2 rows ----
  const int j    = blockIdx.x;          // grid = 384
  const int b    = j & 7;
  const int band = j >> 3;              // 0..47
  const int h0   = band * 2;

  // ---- thread decode: wave = dy, lane = (row, pxg) ----
  const int tid = threadIdx.x;          // 0..575
  const int dy  = tid >> 6;             // 0..8
  const int r   = (tid >> 5) & 1;       // row within band
  const int pxg = tid & 31;             // 4-px group
  const int px0 = pxg << 2;
  const int h   = h0 + r;

  __shared__ float lds[KC][SLOTS][LDW];
  float* const lp = &lds[0][0][0];

  // ---- staging decode: 6 float4 pieces per thread per chunk ----
  // piece f = tid + 576k: c = f/384, slot = (f%384)>>5, pg = f&31
  // slot 0,1 -> in1 rows h0,h0+1 ; slot 2..11 -> in2 rows clamp(h0-4..h0+5)
  const float* gp[6];
  int lw[6];
  bool val[6];
#pragma unroll
  for (int k = 0; k < 6; ++k) {
    const int f = tid + 576 * k;
    val[k] = (f < PIECES);
    const int fc = val[k] ? f : 0;
    const int c   = fc / (SLOTS * 32);
    const int rem = fc - c * (SLOTS * 32);
    const int sl  = rem >> 5;
    const int pg  = rem & 31;
    lw[k] = (c * SLOTS + sl) * LDW + pg * 4;
    int row;
    const float* basep;
    if (sl < 2) { row = h0 + sl; basep = in1; }
    else {
      row = h0 - 6 + sl;                       // h0-4 .. h0+5
      row = row < 0 ? 0 : (row > HH - 1 ? HH - 1 : row);
      basep = in2;
    }
    gp[k] = basep + ((size_t)(b * CH + c) * HH + row) * WW + pg * 4;
  }

  float acc[9][4];
#pragma unroll
  for (int d = 0; d < 9; ++d)
#pragma unroll
    for (int p = 0; p < 4; ++p) acc[d][p] = 0.f;

  // ---- prologue: load chunk 0 into regs ----
  float4 L0, L1, L2, L3, L4, L5;
  if (val[0]) L0 = *(const float4*)gp[0];
  if (val[1]) L1 = *(const float4*)gp[1];
  if (val[2]) L2 = *(const float4*)gp[2];
  if (val[3]) L3 = *(const float4*)gp[3];
  if (val[4]) L4 = *(const float4*)gp[4];
  if (val[5]) L5 = *(const float4*)gp[5];

  const int in1off = r * LDW + px0;                  // slot r
  const int in2off = (2 + r + dy) * LDW + px0;       // slot 2+r+dy

#pragma unroll 1
  for (int chunk = 0; ; ++chunk) {
    // ---- write staged regs to LDS ----
    if (val[0]) *(float4*)(lp + lw[0]) = L0;
    if (val[1]) *(float4*)(lp + lw[1]) = L1;
    if (val[2]) *(float4*)(lp + lw[2]) = L2;
    if (val[3]) *(float4*)(lp + lw[3]) = L3;
    if (val[4]) *(float4*)(lp + lw[4]) = L4;
    if (val[5]) *(float4*)(lp + lw[5]) = L5;
    __syncthreads();

    // ---- issue next chunk's global loads (in flight during compute) ----
    if (chunk < NCHUNK - 1) {
      if (val[0]) { gp[0] += (size_t)KC * CS; L0 = *(const float4*)gp[0]; }
      if (val[1]) { gp[1] += (size_t)KC * CS; L1 = *(const float4*)gp[1]; }
      if (val[2]) { gp[2] += (size_t)KC * CS; L2 = *(const float4*)gp[2]; }
      if (val[3]) { gp[3] += (size_t)KC * CS; L3 = *(const float4*)gp[3]; }
      if (val[4]) { gp[4] += (size_t)KC * CS; L4 = *(const float4*)gp[4]; }
      if (val[5]) { gp[5] += (size_t)KC * CS; L5 = *(const float4*)gp[5]; }
    }

    // ---- compute 8 channels from LDS ----
#pragma unroll
    for (int cc = 0; cc < KC; ++cc) {
      const float4 a4 = *(const float4*)(lp + cc * (SLOTS * LDW) + in1off);
      const float4 m  = *(const float4*)(lp + cc * (SLOTS * LDW) + in2off);

      // w[i] = in2 col (px0 - 4 + i), i = 0..11 (R4-proven 12-DPP window)
      float w[12];
      w[0] = wshr1(m.x); w[1] = wshr1(m.y); w[2] = wshr1(m.z); w[3] = wshr1(m.w);
      w[4] = m.x; w[5] = m.y; w[6] = m.z; w[7] = m.w;
      w[8] = wshl1(m.x); w[9] = wshl1(m.y); w[10] = wshl1(m.z); w[11] = wshl1(m.w);

      const float av[4] = {a4.x, a4.y, a4.z, a4.w};
#pragma unroll
      for (int d = 0; d < 9; ++d)
#pragma unroll
        for (int p = 0; p < 4; ++p)
          acc[d][p] = fmaf(av[p], w[p + d], acc[d][p]);
    }

    if (chunk == NCHUNK - 1) break;
    __syncthreads();   // all reads done before next chunk overwrites
  }

  // ---- epilogue: zero OOB (row+col, incl. DPP edge wrap), scale, store ----
  const float sc = 1.0f / (float)CH;
  const bool rowok = (unsigned)(h + dy - 4) < (unsigned)HH;
  float* po = out + (((size_t)b * 81 + dy * 9) * HH + h) * WW + px0;
#pragma unroll
  for (int d = 0; d < 9; ++d) {
    float v[4];
#pragma unroll
    for (int p = 0; p < 4; ++p) {
      const int col2 = px0 + p + d - 4;                    // in2 column
      v[p] = (rowok && (unsigned)col2 < (unsigned)WW) ? acc[d][p] * sc : 0.f;
    }
    *(float4*)po = make_float4(v[0], v[1], v[2], v[3]);
    po += (size_t)CS;  // next dx plane
  }
}

extern "C" void kernel_launch(void* const* d_in, const int* in_sizes, int n_in,
                              void* d_out, int out_size, void* d_ws, size_t ws_size,
                              hipStream_t stream) {
  const float* in1 = (const float*)d_in[0];
  const float* in2 = (const float*)d_in[1];
  float* out = (float*)d_out;
  hipLaunchKernelGGL(corr_lds, dim3(384), dim3(576), 0, stream, in1, in2, out);
}